// Round 3
// baseline (214.799 us; speedup 1.0000x reference)
//
#include <hip/hip_runtime.h>
#include <stdint.h>

#define B_ 8
#define T_ 2048
#define C_ 1024
#define H_ 64
#define M_ (B_*T_)   // 16384 rows

typedef __bf16 bf16x8 __attribute__((ext_vector_type(8)));
typedef float  f32x4  __attribute__((ext_vector_type(4)));

union U4B { uint4 u; bf16x8 v; };

__device__ __forceinline__ unsigned short f32_to_bf16(float f) {
    union { float f; uint32_t u; } c; c.f = f;
    uint32_t u = c.u;
    u += 0x7fffu + ((u >> 16) & 1u);   // RNE
    return (unsigned short)(u >> 16);
}
__device__ __forceinline__ uint32_t pack2_bf16(float a, float b) {
    return (uint32_t)f32_to_bf16(a) | ((uint32_t)f32_to_bf16(b) << 16);
}

// ---------------- Kernel 1: prepack weights -> bf16 transposed [192][1024] ----
// LDS transpose: coalesced reads AND writes. grid (16, 3).
__global__ __launch_bounds__(256) void prepack_w(const float* __restrict__ Wq,
        const float* __restrict__ Wk, const float* __restrict__ Wv,
        unsigned short* __restrict__ wt) {
    __shared__ unsigned short tile[64][72];
    const int which = blockIdx.y;
    const int k0 = blockIdx.x * 64;
    const float* W = (which == 0) ? Wq : (which == 1) ? Wk : Wv;
    const int tid = threadIdx.x;
    for (int i = 0; i < 4; i++) {
        int e = tid + 256 * i;           // 1024 float4 chunks = 64 k-rows x 16
        int kk = e >> 4, c4 = (e & 15) * 4;
        float4 w = *(const float4*)(W + (size_t)(k0 + kk) * 64 + c4);
        unsigned short* p = &tile[kk][c4];
        p[0] = f32_to_bf16(w.x); p[1] = f32_to_bf16(w.y);
        p[2] = f32_to_bf16(w.z); p[3] = f32_to_bf16(w.w);
    }
    __syncthreads();
    for (int i = 0; i < 2; i++) {
        int e = tid + 256 * i;           // 512 chunks = 64 cols x 8
        int col = e >> 3, k8 = (e & 7) * 8;
        unsigned short tmp[8];
        for (int j = 0; j < 8; j++) tmp[j] = tile[k8 + j][col];
        *(uint4*)(wt + (size_t)(which * 64 + col) * 1024 + k0 + k8) = *(uint4*)tmp;
    }
}

// ---------------- Kernel 2: QKV projection (barrier-free, no LDS) ------------
// 1024 blocks x 256 thr; block = 16 rows; wave w computes nt = 3w..3w+2.
// A-frags: X fp32 read directly in A-layout (row=l15, k=grp*8+j), packed in-reg.
__global__ __launch_bounds__(256) void qkv_kernel(const float* __restrict__ X,
        const unsigned short* __restrict__ wt,
        unsigned short* __restrict__ qb, unsigned short* __restrict__ kb,
        unsigned short* __restrict__ vb) {
    const int tid = threadIdx.x;
    const int wave = tid >> 6, lane = tid & 63;
    const int grp = lane >> 4, l15 = lane & 15;
    const int row = blockIdx.x * 16 + l15;
    const float* xp = X + (size_t)row * 1024 + grp * 8;

    f32x4 acc[3];
    for (int i = 0; i < 3; i++) acc[i] = (f32x4){0.f, 0.f, 0.f, 0.f};

    float4 f0 = *(const float4*)(xp);
    float4 f1 = *(const float4*)(xp + 4);
    for (int k0 = 0; k0 < 1024; k0 += 32) {
        U4B ua;
        ua.u = (uint4){ pack2_bf16(f0.x, f0.y), pack2_bf16(f0.z, f0.w),
                        pack2_bf16(f1.x, f1.y), pack2_bf16(f1.z, f1.w) };
        if (k0 + 32 < 1024) {             // prefetch next k-chunk
            f0 = *(const float4*)(xp + k0 + 32);
            f1 = *(const float4*)(xp + k0 + 36);
        }
        #pragma unroll
        for (int j = 0; j < 3; j++) {
            int nt = wave * 3 + j;
            const unsigned short* wp = wt + (size_t)(nt * 16 + l15) * 1024 + k0 + grp * 8;
            bf16x8 bfr = *(const bf16x8*)wp;
            acc[j] = __builtin_amdgcn_mfma_f32_16x16x32_bf16(ua.v, bfr, acc[j], 0, 0, 0);
        }
    }
    int r0 = blockIdx.x * 16 + grp * 4;
    #pragma unroll
    for (int j = 0; j < 3; j++) {
        int col = (wave * 3 + j) * 16 + l15;
        unsigned short* dst = (col < 64) ? qb : (col < 128) ? kb : vb;
        int c = col & 63;
        float sc = (col < 64) ? 0.03125f : 1.0f;   // fold C^-0.5 into q
        for (int r = 0; r < 4; r++)
            dst[(size_t)(r0 + r) * 64 + c] = f32_to_bf16(acc[j][r] * sc);
    }
}

// ---------------- Kernel 3: transpose V -> vt[B][64][2048] --------------------
__global__ __launch_bounds__(256) void vtrans_kernel(const unsigned short* __restrict__ vb,
                                                     unsigned short* __restrict__ vt) {
    __shared__ unsigned short tile[64][72];
    const int b = blockIdx.y, t0 = blockIdx.x * 64;
    const int tid = threadIdx.x;
    for (int i = 0; i < 2; i++) {
        int chunk = tid + 256 * i;
        int row = chunk >> 3, c8 = (chunk & 7) * 8;
        *(uint4*)&tile[row][c8] = *(const uint4*)(vb + ((size_t)(b * 2048 + t0 + row)) * 64 + c8);
    }
    __syncthreads();
    for (int i = 0; i < 2; i++) {
        int chunk = tid + 256 * i;
        int d = chunk >> 3, t8 = (chunk & 7) * 8;
        unsigned short tmp[8];
        for (int j = 0; j < 8; j++) tmp[j] = tile[t8 + j][d];
        *(uint4*)(vt + ((size_t)b * 64 + d) * 2048 + t0 + t8) = *(uint4*)tmp;
    }
}

// ---------------- Kernel 4: attention pass 1 (S^T formulation) ----------------
// Wave computes S^T = K Q^T so softmax state is lane-scalar (q = l15).
// O^T = V^T P^T accumulated transposed; P^T C/D->B-frag via shfl (no LDS/barrier).
// grid (80, 8) x 256 thr; 4 independent waves/block; f = heavy-first.
__global__ __launch_bounds__(256) void attn1_kernel(const unsigned short* __restrict__ qb,
        const unsigned short* __restrict__ kb, const unsigned short* __restrict__ vt,
        float* __restrict__ pm, float* __restrict__ pl, float* __restrict__ pacc) {
    const int lane = threadIdx.x & 63;
    const int wave = threadIdx.x >> 6;
    const int grp = lane >> 4, l15 = lane & 15;
    const int b = blockIdx.y;
    int f = 319 - (blockIdx.x * 4 + wave);
    int qt, s;
    if (f < 32)       { qt = f;                  s = 0; }
    else if (f < 96)  { qt = 32 + (f - 32) / 2;  s = (f - 32) % 2; }
    else if (f < 192) { qt = 64 + (f - 96) / 3;  s = (f - 96) % 3; }
    else              { qt = 96 + (f - 192) / 4; s = (f - 192) % 4; }
    const int qbase = qt * 16;
    const int kstart = s * 512;
    const int kend = min(kstart + 512, qbase + 16);

    // Q as B-frag: B[k=h=grp*8+j][n=q=l15]
    const unsigned short* qp = qb + ((size_t)b * 2048 + qbase + l15) * 64 + grp * 8;
    bf16x8 bq0 = *(const bf16x8*)qp;
    bf16x8 bq1 = *(const bf16x8*)(qp + 32);

    float m_i = -1e30f, l_i = 0.f;
    f32x4 acc[4];
    for (int d = 0; d < 4; d++) acc[d] = (f32x4){0.f, 0.f, 0.f, 0.f};

    for (int kc = kstart; kc < kend; kc += 32) {
        const bool have2 = (kc + 16) < kend;
        // --- S^T tiles: A = K rows (key=l15), B = Q^T ---
        const unsigned short* kp0 = kb + ((size_t)b * 2048 + kc + l15) * 64 + grp * 8;
        bf16x8 ak00 = *(const bf16x8*)kp0;
        bf16x8 ak01 = *(const bf16x8*)(kp0 + 32);
        f32x4 st0 = (f32x4){0.f, 0.f, 0.f, 0.f};
        st0 = __builtin_amdgcn_mfma_f32_16x16x32_bf16(ak00, bq0, st0, 0, 0, 0);
        st0 = __builtin_amdgcn_mfma_f32_16x16x32_bf16(ak01, bq1, st0, 0, 0, 0);
        f32x4 st1 = (f32x4){0.f, 0.f, 0.f, 0.f};
        if (have2) {
            const unsigned short* kp1 = kp0 + 16 * 64;
            bf16x8 ak10 = *(const bf16x8*)kp1;
            bf16x8 ak11 = *(const bf16x8*)(kp1 + 32);
            st1 = __builtin_amdgcn_mfma_f32_16x16x32_bf16(ak10, bq0, st1, 0, 0, 0);
            st1 = __builtin_amdgcn_mfma_f32_16x16x32_bf16(ak11, bq1, st1, 0, 0, 0);
        }
        // --- causal mask (key > q) on diagonal chunks; q = qbase+l15 ---
        if (kc + 31 >= qbase) {
            int q = qbase + l15;
            #pragma unroll
            for (int r = 0; r < 4; r++) {
                if (kc + grp * 4 + r > q)      st0[r] = -1e30f;
                if (kc + 16 + grp * 4 + r > q) st1[r] = -1e30f;
            }
        }
        // --- online softmax, lane-scalar state ---
        float tmax = fmaxf(fmaxf(st0[0], st0[1]), fmaxf(st0[2], st0[3]));
        if (have2) tmax = fmaxf(tmax, fmaxf(fmaxf(st1[0], st1[1]), fmaxf(st1[2], st1[3])));
        tmax = fmaxf(tmax, __shfl_xor(tmax, 16, 64));
        tmax = fmaxf(tmax, __shfl_xor(tmax, 32, 64));
        float mnew = fmaxf(m_i, tmax);
        float alpha = __expf(m_i - mnew);
        m_i = mnew;
        float p0[4], p1[4];
        float ts = 0.f;
        #pragma unroll
        for (int r = 0; r < 4; r++) { p0[r] = __expf(st0[r] - mnew); ts += p0[r]; }
        if (have2) {
            #pragma unroll
            for (int r = 0; r < 4; r++) { p1[r] = __expf(st1[r] - mnew); ts += p1[r]; }
        } else {
            for (int r = 0; r < 4; r++) p1[r] = 0.f;
        }
        ts += __shfl_xor(ts, 16, 64);
        ts += __shfl_xor(ts, 32, 64);
        l_i = l_i * alpha + ts;
        #pragma unroll
        for (int d = 0; d < 4; d++) acc[d] *= alpha;
        // --- P^T (C/D layout: key=grp*4+r, q=l15) -> B-frag (k=grp*8+j, n=l15) ---
        uint32_t t0a = pack2_bf16(p0[0], p0[1]), t0b = pack2_bf16(p0[2], p0[3]);
        uint32_t t1a = pack2_bf16(p1[0], p1[1]), t1b = pack2_bf16(p1[2], p1[3]);
        int s0l = ((grp & 1) << 5) + l15;   // src grp 2*(g&1)
        int s1l = s0l + 16;                 // src grp 2*(g&1)+1
        uint32_t e0a = (uint32_t)__shfl((int)t0a, s0l, 64);
        uint32_t e0b = (uint32_t)__shfl((int)t0b, s0l, 64);
        uint32_t e0c = (uint32_t)__shfl((int)t0a, s1l, 64);
        uint32_t e0d = (uint32_t)__shfl((int)t0b, s1l, 64);
        uint32_t e1a = (uint32_t)__shfl((int)t1a, s0l, 64);
        uint32_t e1b = (uint32_t)__shfl((int)t1b, s0l, 64);
        uint32_t e1c = (uint32_t)__shfl((int)t1a, s1l, 64);
        uint32_t e1d = (uint32_t)__shfl((int)t1b, s1l, 64);
        bool hi = (grp >= 2);               // grp 0,1 -> tile0 keys; grp 2,3 -> tile1
        U4B bw;
        bw.u = (uint4){ hi ? e1a : e0a, hi ? e1b : e0b, hi ? e1c : e0c, hi ? e1d : e0d };
        // --- O^T += V^T P^T : A = V^T rows (d = dt*16+l15, k = key) ---
        const unsigned short* vp = vt + ((size_t)b * 64 + l15) * 2048 + kc + grp * 8;
        #pragma unroll
        for (int dt = 0; dt < 4; dt++) {
            bf16x8 av = *(const bf16x8*)(vp + (size_t)dt * 16 * 2048);
            acc[dt] = __builtin_amdgcn_mfma_f32_16x16x32_bf16(av, bw.v, acc[dt], 0, 0, 0);
        }
    }
    // --- partials: per-lane q = l15 (state replicated over grp) ---
    size_t rowq = (size_t)b * 2048 + qbase + l15;
    size_t p = rowq * 4 + s;
    if (grp == 0) { pm[p] = m_i; pl[p] = l_i; }
    #pragma unroll
    for (int dt = 0; dt < 4; dt++)
        *(f32x4*)&pacc[p * 64 + dt * 16 + grp * 4] = acc[dt];
}

// ---------------- Kernel 5: attention pass 2 (combine segments) ---------------
__global__ __launch_bounds__(256) void attn2_kernel(const float* __restrict__ pm,
        const float* __restrict__ pl, const float* __restrict__ pacc,
        float* __restrict__ out) {
    int idx = blockIdx.x * 256 + threadIdx.x;     // 16384*16
    int row = idx >> 4;
    int d0 = (idx & 15) * 4;
    int t = row & 2047;
    int ns = (t >> 9) + 1;
    float mv[4];
    float M = -1e30f;
    for (int s = 0; s < ns; s++) { mv[s] = pm[(size_t)row * 4 + s]; M = fmaxf(M, mv[s]); }
    float den = 0.f;
    f32x4 num = (f32x4){0.f, 0.f, 0.f, 0.f};
    for (int s = 0; s < ns; s++) {
        float w = __expf(mv[s] - M);
        den += w * pl[(size_t)row * 4 + s];
        f32x4 a = *(const f32x4*)&pacc[((size_t)row * 4 + s) * 64 + d0];
        num += w * a;
    }
    float inv = 1.f / den;
    *(f32x4*)&out[(size_t)row * 64 + d0] = num * inv;
}

extern "C" void kernel_launch(void* const* d_in, const int* in_sizes, int n_in,
                              void* d_out, int out_size, void* d_ws, size_t ws_size,
                              hipStream_t stream) {
    const float* X  = (const float*)d_in[0];
    const float* Wq = (const float*)d_in[1];
    const float* Wk = (const float*)d_in[2];
    const float* Wv = (const float*)d_in[3];
    float* out = (float*)d_out;

    unsigned short* qb = (unsigned short*)d_ws;          // [16384][64] bf16 (q pre-scaled)
    unsigned short* kb = qb + (size_t)M_ * 64;
    unsigned short* vb = kb + (size_t)M_ * 64;
    unsigned short* wt = vb + (size_t)M_ * 64;           // [192][1024]
    unsigned short* vt = wt + (size_t)192 * 1024;        // [8][64][2048]
    float* pm   = (float*)(vt + (size_t)B_ * 64 * 2048); // [16384][4]
    float* pl   = pm + (size_t)M_ * 4;                   // [16384][4]
    float* pacc = pl + (size_t)M_ * 4;                   // [16384][4][64]

    prepack_w<<<dim3(16, 3), 256, 0, stream>>>(Wq, Wk, Wv, wt);
    qkv_kernel<<<1024, 256, 0, stream>>>(X, wt, qb, kb, vb);
    vtrans_kernel<<<dim3(32, 8), 256, 0, stream>>>(vb, vt);
    attn1_kernel<<<dim3(80, 8), 256, 0, stream>>>(qb, kb, vt, pm, pl, pacc);
    attn2_kernel<<<1024, 256, 0, stream>>>(pm, pl, pacc, out);
}

// Round 4
// 186.593 us; speedup vs baseline: 1.1512x; 1.1512x over previous
//
#include <hip/hip_runtime.h>
#include <stdint.h>

#define B_ 8
#define T_ 2048
#define C_ 1024
#define H_ 64
#define M_ (B_*T_)   // 16384 rows

typedef __bf16 bf16x8 __attribute__((ext_vector_type(8)));
typedef float  f32x4  __attribute__((ext_vector_type(4)));

union U4B { uint4 u; bf16x8 v; };

__device__ __forceinline__ unsigned short f32_to_bf16(float f) {
    union { float f; uint32_t u; } c; c.f = f;
    uint32_t u = c.u;
    u += 0x7fffu + ((u >> 16) & 1u);   // RNE
    return (unsigned short)(u >> 16);
}
__device__ __forceinline__ uint32_t pack2_bf16(float a, float b) {
    return (uint32_t)f32_to_bf16(a) | ((uint32_t)f32_to_bf16(b) << 16);
}

// ---------------- Kernel 1: prepack weights -> bf16 transposed [192][1024] ----
__global__ __launch_bounds__(256) void prepack_w(const float* __restrict__ Wq,
        const float* __restrict__ Wk, const float* __restrict__ Wv,
        unsigned short* __restrict__ wt) {
    __shared__ unsigned short tile[64][72];
    const int which = blockIdx.y;
    const int k0 = blockIdx.x * 64;
    const float* W = (which == 0) ? Wq : (which == 1) ? Wk : Wv;
    const int tid = threadIdx.x;
    for (int i = 0; i < 4; i++) {
        int e = tid + 256 * i;
        int kk = e >> 4, c4 = (e & 15) * 4;
        float4 w = *(const float4*)(W + (size_t)(k0 + kk) * 64 + c4);
        unsigned short* p = &tile[kk][c4];
        p[0] = f32_to_bf16(w.x); p[1] = f32_to_bf16(w.y);
        p[2] = f32_to_bf16(w.z); p[3] = f32_to_bf16(w.w);
    }
    __syncthreads();
    for (int i = 0; i < 2; i++) {
        int e = tid + 256 * i;
        int col = e >> 3, k8 = (e & 7) * 8;
        unsigned short tmp[8];
        for (int j = 0; j < 8; j++) tmp[j] = tile[k8 + j][col];
        *(uint4*)(wt + (size_t)(which * 64 + col) * 1024 + k0 + k8) = *(uint4*)tmp;
    }
}

// ---------------- Kernel 2: QKV projection (2-phase pipelined, no LDS) -------
// 1024 blocks x 256 thr; block = 16 rows; wave w -> output col-tiles 3w..3w+2.
// Both X (A-frag) and W (B-frag) loads run one 64-k iteration ahead of MFMA.
// V written directly transposed -> vt[b][dim][t].
__global__ __launch_bounds__(256, 4) void qkv_kernel(const float* __restrict__ X,
        const unsigned short* __restrict__ wt,
        unsigned short* __restrict__ qb, unsigned short* __restrict__ kb,
        unsigned short* __restrict__ vt) {
    const int tid = threadIdx.x;
    const int wave = tid >> 6, lane = tid & 63;
    const int grp = lane >> 4, l15 = lane & 15;
    const int rowblk = blockIdx.x * 16;
    const float* xp = X + (size_t)(rowblk + l15) * 1024 + grp * 8;
    const unsigned short* wpB = wt + (size_t)(wave * 48 + l15) * 1024 + grp * 8;

    f32x4 acc[3];
    for (int i = 0; i < 3; i++) acc[i] = (f32x4){0.f, 0.f, 0.f, 0.f};

    float4 xr[2][4];
    uint4  wr[2][6];
    // phase-0 loads (k = 0..63)
    xr[0][0] = *(const float4*)(xp + 0);
    xr[0][1] = *(const float4*)(xp + 4);
    xr[0][2] = *(const float4*)(xp + 32);
    xr[0][3] = *(const float4*)(xp + 36);
    #pragma unroll
    for (int jj = 0; jj < 3; jj++) {
        wr[0][jj * 2]     = *(const uint4*)(wpB + jj * 16384);
        wr[0][jj * 2 + 1] = *(const uint4*)(wpB + jj * 16384 + 32);
    }
    #pragma unroll
    for (int it = 0; it < 16; it++) {
        const int ph = it & 1, np = ph ^ 1;
        if (it < 15) {
            const int kn = (it + 1) * 64;
            xr[np][0] = *(const float4*)(xp + kn);
            xr[np][1] = *(const float4*)(xp + kn + 4);
            xr[np][2] = *(const float4*)(xp + kn + 32);
            xr[np][3] = *(const float4*)(xp + kn + 36);
            #pragma unroll
            for (int jj = 0; jj < 3; jj++) {
                wr[np][jj * 2]     = *(const uint4*)(wpB + jj * 16384 + kn);
                wr[np][jj * 2 + 1] = *(const uint4*)(wpB + jj * 16384 + kn + 32);
            }
        }
        U4B a0, a1;
        a0.u = (uint4){ pack2_bf16(xr[ph][0].x, xr[ph][0].y), pack2_bf16(xr[ph][0].z, xr[ph][0].w),
                        pack2_bf16(xr[ph][1].x, xr[ph][1].y), pack2_bf16(xr[ph][1].z, xr[ph][1].w) };
        a1.u = (uint4){ pack2_bf16(xr[ph][2].x, xr[ph][2].y), pack2_bf16(xr[ph][2].z, xr[ph][2].w),
                        pack2_bf16(xr[ph][3].x, xr[ph][3].y), pack2_bf16(xr[ph][3].z, xr[ph][3].w) };
        #pragma unroll
        for (int jj = 0; jj < 3; jj++) {
            U4B b0, b1; b0.u = wr[ph][jj * 2]; b1.u = wr[ph][jj * 2 + 1];
            acc[jj] = __builtin_amdgcn_mfma_f32_16x16x32_bf16(a0.v, b0.v, acc[jj], 0, 0, 0);
            acc[jj] = __builtin_amdgcn_mfma_f32_16x16x32_bf16(a1.v, b1.v, acc[jj], 0, 0, 0);
        }
    }
    // epilogue: D row = grp*4+r (token), col = (wave*3+jj)*16 + l15
    const int r0 = rowblk + grp * 4;
    const int bb = rowblk >> 11;
    const int t0 = (rowblk + grp * 4) & 2047;
    #pragma unroll
    for (int jj = 0; jj < 3; jj++) {
        int col = (wave * 3 + jj) * 16 + l15;
        if (col < 64) {
            for (int r = 0; r < 4; r++)
                qb[(size_t)(r0 + r) * 64 + col] = f32_to_bf16(acc[jj][r] * 0.03125f);
        } else if (col < 128) {
            for (int r = 0; r < 4; r++)
                kb[(size_t)(r0 + r) * 64 + (col - 64)] = f32_to_bf16(acc[jj][r]);
        } else {
            int c = col - 128;
            ushort4 vv;
            vv.x = f32_to_bf16(acc[jj][0]); vv.y = f32_to_bf16(acc[jj][1]);
            vv.z = f32_to_bf16(acc[jj][2]); vv.w = f32_to_bf16(acc[jj][3]);
            *(ushort4*)(vt + ((size_t)bb * 64 + c) * 2048 + t0) = vv;
        }
    }
}

// ---------------- Kernel 3: attention pass 1 --------------------------------
// Block: 256 thr = 4 waves sharing LDS K/V tiles (64 keys), q-tile = 64 rows
// (16/wave). Key segment = 512 keys -> <=8 tiles/block. S^T formulation:
// lane-scalar softmax (2 shuffles), P^T->B-frag via shuffles, double-buffered
// staging, 1 barrier/iter.
__global__ __launch_bounds__(256) void attn1_kernel(const unsigned short* __restrict__ qb,
        const unsigned short* __restrict__ kb, const unsigned short* __restrict__ vt,
        float* __restrict__ pm, float* __restrict__ pl, float* __restrict__ pacc) {
    __shared__ unsigned short Kl[2][64][72];   // [key][dim]
    __shared__ unsigned short Vl[2][64][72];   // [dim][key]
    const int tid = threadIdx.x;
    const int wave = tid >> 6, lane = tid & 63;
    const int grp = lane >> 4, l15 = lane & 15;
    const int b = blockIdx.y;
    const int f = blockIdx.x;                  // 80 blocks/batch, heavy-first per s
    int s, j;
    if (f < 32)      { s = 0; j = 31 - f; }
    else if (f < 56) { s = 1; j = 31 - (f - 32); }
    else if (f < 72) { s = 2; j = 31 - (f - 56); }
    else             { s = 3; j = 31 - (f - 72); }
    const int qbase = j * 64 + wave * 16;      // wave's 16 q rows
    const int ktend = min(8, j + 1 - 8 * s);   // 64-key tiles in this segment

    // Q B-frags (k = h = grp*8+jj, n = q = l15); q pre-scaled by C^-0.5
    const unsigned short* qp = qb + ((size_t)b * 2048 + qbase + l15) * 64 + grp * 8;
    bf16x8 bq0 = *(const bf16x8*)qp;
    bf16x8 bq1 = *(const bf16x8*)(qp + 32);

    float m_i = -1e30f, l_i = 0.f;
    f32x4 acc[4];
    for (int d = 0; d < 4; d++) acc[d] = (f32x4){0.f, 0.f, 0.f, 0.f};

    const unsigned short* kB = kb + ((size_t)b * 2048 + s * 512) * 64;
    const unsigned short* vB = vt + (size_t)b * 64 * 2048 + s * 512;
    const int r1 = tid >> 3, c1 = (tid & 7) * 8;          // chunk 0: rows 0..31
    const int r2 = (tid + 256) >> 3, c2 = c1;             // chunk 1: rows 32..63

    uint4 kr0, kr1, vr0, vr1;
    // prologue: load tile 0
    kr0 = *(const uint4*)(kB + (size_t)r1 * 64 + c1);
    kr1 = *(const uint4*)(kB + (size_t)r2 * 64 + c2);
    vr0 = *(const uint4*)(vB + (size_t)r1 * 2048 + c1);
    vr1 = *(const uint4*)(vB + (size_t)r2 * 2048 + c2);
    *(uint4*)&Kl[0][r1][c1] = kr0;  *(uint4*)&Kl[0][r2][c2] = kr1;
    *(uint4*)&Vl[0][r1][c1] = vr0;  *(uint4*)&Vl[0][r2][c2] = vr1;
    __syncthreads();

    for (int kt = 0; kt < ktend; kt++) {
        const int buf = kt & 1;
        const bool more = (kt + 1) < ktend;
        if (more) {   // issue next tile's global loads (consumed after compute)
            const unsigned short* kN = kB + (size_t)(kt + 1) * 64 * 64;
            const unsigned short* vN = vB + (kt + 1) * 64;
            kr0 = *(const uint4*)(kN + (size_t)r1 * 64 + c1);
            kr1 = *(const uint4*)(kN + (size_t)r2 * 64 + c2);
            vr0 = *(const uint4*)(vN + (size_t)r1 * 2048 + c1);
            vr1 = *(const uint4*)(vN + (size_t)r2 * 2048 + c2);
        }
        const int keybase = s * 512 + kt * 64;
        // ---- S^T = K Q^T : 4 key-subtiles ----
        f32x4 st[4];
        #pragma unroll
        for (int nt = 0; nt < 4; nt++) {
            bf16x8 a0 = *(const bf16x8*)&Kl[buf][nt * 16 + l15][grp * 8];
            bf16x8 a1 = *(const bf16x8*)&Kl[buf][nt * 16 + l15][32 + grp * 8];
            f32x4 t = (f32x4){0.f, 0.f, 0.f, 0.f};
            t = __builtin_amdgcn_mfma_f32_16x16x32_bf16(a0, bq0, t, 0, 0, 0);
            t = __builtin_amdgcn_mfma_f32_16x16x32_bf16(a1, bq1, t, 0, 0, 0);
            st[nt] = t;
        }
        // ---- causal mask (key > q); skip when tile entirely below diagonal ----
        if (keybase + 63 > qbase) {
            int q = qbase + l15;
            #pragma unroll
            for (int nt = 0; nt < 4; nt++)
                for (int r = 0; r < 4; r++)
                    if (keybase + nt * 16 + grp * 4 + r > q) st[nt][r] = -1e30f;
        }
        // ---- online softmax (lane-scalar state, q = l15) ----
        float tmax = -1e30f;
        #pragma unroll
        for (int nt = 0; nt < 4; nt++)
            for (int r = 0; r < 4; r++) tmax = fmaxf(tmax, st[nt][r]);
        tmax = fmaxf(tmax, __shfl_xor(tmax, 16, 64));
        tmax = fmaxf(tmax, __shfl_xor(tmax, 32, 64));
        float mnew = fmaxf(m_i, tmax);
        float alpha = __expf(m_i - mnew);
        m_i = mnew;
        float p[4][4]; float ts = 0.f;
        #pragma unroll
        for (int nt = 0; nt < 4; nt++)
            for (int r = 0; r < 4; r++) { p[nt][r] = __expf(st[nt][r] - mnew); ts += p[nt][r]; }
        ts += __shfl_xor(ts, 16, 64);
        ts += __shfl_xor(ts, 32, 64);
        l_i = l_i * alpha + ts;
        #pragma unroll
        for (int d = 0; d < 4; d++) acc[d] *= alpha;
        // ---- P^T (C/D: key=grp*4+r, q=l15) -> 2 B-frags (k=key, n=q) ----
        uint32_t t0a = pack2_bf16(p[0][0], p[0][1]), t0b = pack2_bf16(p[0][2], p[0][3]);
        uint32_t t1a = pack2_bf16(p[1][0], p[1][1]), t1b = pack2_bf16(p[1][2], p[1][3]);
        uint32_t t2a = pack2_bf16(p[2][0], p[2][1]), t2b = pack2_bf16(p[2][2], p[2][3]);
        uint32_t t3a = pack2_bf16(p[3][0], p[3][1]), t3b = pack2_bf16(p[3][2], p[3][3]);
        const int s0l = ((grp & 1) << 5) + l15, s1l = s0l + 16;
        const bool hi = (grp >= 2);
        U4B bw0, bw1;
        {
            uint32_t e0a = (uint32_t)__shfl((int)t0a, s0l, 64);
            uint32_t e0b = (uint32_t)__shfl((int)t0b, s0l, 64);
            uint32_t e0c = (uint32_t)__shfl((int)t0a, s1l, 64);
            uint32_t e0d = (uint32_t)__shfl((int)t0b, s1l, 64);
            uint32_t e1a = (uint32_t)__shfl((int)t1a, s0l, 64);
            uint32_t e1b = (uint32_t)__shfl((int)t1b, s0l, 64);
            uint32_t e1c = (uint32_t)__shfl((int)t1a, s1l, 64);
            uint32_t e1d = (uint32_t)__shfl((int)t1b, s1l, 64);
            bw0.u = (uint4){ hi ? e1a : e0a, hi ? e1b : e0b, hi ? e1c : e0c, hi ? e1d : e0d };
        }
        {
            uint32_t e0a = (uint32_t)__shfl((int)t2a, s0l, 64);
            uint32_t e0b = (uint32_t)__shfl((int)t2b, s0l, 64);
            uint32_t e0c = (uint32_t)__shfl((int)t2a, s1l, 64);
            uint32_t e0d = (uint32_t)__shfl((int)t2b, s1l, 64);
            uint32_t e1a = (uint32_t)__shfl((int)t3a, s0l, 64);
            uint32_t e1b = (uint32_t)__shfl((int)t3b, s0l, 64);
            uint32_t e1c = (uint32_t)__shfl((int)t3a, s1l, 64);
            uint32_t e1d = (uint32_t)__shfl((int)t3b, s1l, 64);
            bw1.u = (uint4){ hi ? e1a : e0a, hi ? e1b : e0b, hi ? e1c : e0c, hi ? e1d : e0d };
        }
        // ---- O^T += V^T P^T ----
        #pragma unroll
        for (int dt = 0; dt < 4; dt++) {
            bf16x8 av0 = *(const bf16x8*)&Vl[buf][dt * 16 + l15][grp * 8];
            bf16x8 av1 = *(const bf16x8*)&Vl[buf][dt * 16 + l15][32 + grp * 8];
            acc[dt] = __builtin_amdgcn_mfma_f32_16x16x32_bf16(av0, bw0.v, acc[dt], 0, 0, 0);
            acc[dt] = __builtin_amdgcn_mfma_f32_16x16x32_bf16(av1, bw1.v, acc[dt], 0, 0, 0);
        }
        // ---- write next tile into the other buffer ----
        if (more) {
            const int nb = buf ^ 1;
            *(uint4*)&Kl[nb][r1][c1] = kr0;  *(uint4*)&Kl[nb][r2][c2] = kr1;
            *(uint4*)&Vl[nb][r1][c1] = vr0;  *(uint4*)&Vl[nb][r2][c2] = vr1;
        }
        __syncthreads();
    }
    // ---- partials (state replicated over grp; q = l15) ----
    size_t rowq = (size_t)b * 2048 + qbase + l15;
    size_t p = rowq * 4 + s;
    if (grp == 0) { pm[p] = m_i; pl[p] = l_i; }
    #pragma unroll
    for (int dt = 0; dt < 4; dt++)
        *(f32x4*)&pacc[p * 64 + dt * 16 + grp * 4] = acc[dt];
}

// ---------------- Kernel 4: attention pass 2 (combine segments) ---------------
__global__ __launch_bounds__(256) void attn2_kernel(const float* __restrict__ pm,
        const float* __restrict__ pl, const float* __restrict__ pacc,
        float* __restrict__ out) {
    int idx = blockIdx.x * 256 + threadIdx.x;     // 16384*16
    int row = idx >> 4;
    int d0 = (idx & 15) * 4;
    int t = row & 2047;
    int ns = (t >> 9) + 1;
    float mv[4];
    float M = -1e30f;
    for (int s = 0; s < ns; s++) { mv[s] = pm[(size_t)row * 4 + s]; M = fmaxf(M, mv[s]); }
    float den = 0.f;
    f32x4 num = (f32x4){0.f, 0.f, 0.f, 0.f};
    for (int s = 0; s < ns; s++) {
        float w = __expf(mv[s] - M);
        den += w * pl[(size_t)row * 4 + s];
        f32x4 a = *(const f32x4*)&pacc[((size_t)row * 4 + s) * 64 + d0];
        num += w * a;
    }
    float inv = 1.f / den;
    *(f32x4*)&out[(size_t)row * 64 + d0] = num * inv;
}

extern "C" void kernel_launch(void* const* d_in, const int* in_sizes, int n_in,
                              void* d_out, int out_size, void* d_ws, size_t ws_size,
                              hipStream_t stream) {
    const float* X  = (const float*)d_in[0];
    const float* Wq = (const float*)d_in[1];
    const float* Wk = (const float*)d_in[2];
    const float* Wv = (const float*)d_in[3];
    float* out = (float*)d_out;

    unsigned short* qb = (unsigned short*)d_ws;          // [16384][64] bf16 (q pre-scaled)
    unsigned short* kb = qb + (size_t)M_ * 64;           // [16384][64]
    unsigned short* wt = kb + (size_t)M_ * 64;           // [192][1024]
    unsigned short* vt = wt + (size_t)192 * 1024;        // [8][64][2048]
    float* pm   = (float*)(vt + (size_t)B_ * 64 * 2048); // [16384][4]
    float* pl   = pm + (size_t)M_ * 4;                   // [16384][4]
    float* pacc = pl + (size_t)M_ * 4;                   // [16384][4][64]

    prepack_w<<<dim3(16, 3), 256, 0, stream>>>(Wq, Wk, Wv, wt);
    qkv_kernel<<<1024, 256, 0, stream>>>(X, wt, qb, kb, vt);
    attn1_kernel<<<dim3(80, 8), 256, 0, stream>>>(qb, kb, vt, pm, pl, pacc);
    attn2_kernel<<<1024, 256, 0, stream>>>(pm, pl, pacc, out);
}

// Round 5
// 146.390 us; speedup vs baseline: 1.4673x; 1.2746x over previous
//
#include <hip/hip_runtime.h>
#include <stdint.h>

#define B_ 8
#define T_ 2048
#define C_ 1024
#define H_ 64
#define M_ (B_*T_)   // 16384 rows

typedef __bf16 bf16x8 __attribute__((ext_vector_type(8)));
typedef float  f32x4  __attribute__((ext_vector_type(4)));

union U4B { uint4 u; bf16x8 v; };

__device__ __forceinline__ unsigned short f32_to_bf16(float f) {
    union { float f; uint32_t u; } c; c.f = f;
    uint32_t u = c.u;
    u += 0x7fffu + ((u >> 16) & 1u);   // RNE
    return (unsigned short)(u >> 16);
}
__device__ __forceinline__ uint32_t pack2_bf16(float a, float b) {
    return (uint32_t)f32_to_bf16(a) | ((uint32_t)f32_to_bf16(b) << 16);
}

// ---------------- Kernel 1: prepack W -> bf16 in B-FRAGMENT order ------------
// wpk element layout: chunk o = (nt*32 + kc)*64 + lane, lane=(grp*16+l15),
// holds W[n = nt*16+l15][k = kc*32 + grp*8 + j], j=0..7. A B-frag load in the
// GEMM is then lane->base+lane*16B: one contiguous 1KB wave-load.
__global__ __launch_bounds__(256) void prepack_w(const float* __restrict__ Wq,
        const float* __restrict__ Wk, const float* __restrict__ Wv,
        unsigned short* __restrict__ wpk) {
    int o = blockIdx.x * 256 + threadIdx.x;      // 0..24575
    if (o >= 24576) return;
    int lane = o & 63, kc = (o >> 6) & 31, nt = o >> 11;
    int l15 = lane & 15, grp = lane >> 4;
    int n = nt * 16 + l15;                        // global col 0..191
    int k = kc * 32 + grp * 8;
    const float* W = (n < 64) ? Wq : (n < 128) ? Wk : Wv;
    int col = n & 63;
    unsigned short tmp[8];
    #pragma unroll
    for (int j = 0; j < 8; j++) tmp[j] = f32_to_bf16(W[(size_t)(k + j) * 64 + col]);
    *(uint4*)(wpk + (size_t)o * 8) = *(uint4*)tmp;
}

// ---------------- Kernel 2: QKV projection ------------------------------------
// grid 1024 x 256 thr (4 waves). Block = 16 rows; wave w -> col-tiles 3w..3w+2.
// X: coalesced fp32 -> LDS bf16 tile (16x64), A-frags via ds_read_b128.
// W: contiguous fragment loads from wpk, register double-buffered.
__global__ __launch_bounds__(256, 4) void qkv_kernel(const float* __restrict__ X,
        const unsigned short* __restrict__ wpk,
        unsigned short* __restrict__ qb, unsigned short* __restrict__ kb,
        unsigned short* __restrict__ vt) {
    __shared__ unsigned short Xl[16][72];
    const int tid = threadIdx.x;
    const int wave = tid >> 6, lane = tid & 63;
    const int grp = lane >> 4, l15 = lane & 15;
    const int mb = blockIdx.x * 16;
    const int srow = tid >> 4, sc4 = (tid & 15) * 4;   // staging: 16 rows x 64 f32

    f32x4 acc[3];
    for (int i = 0; i < 3; i++) acc[i] = (f32x4){0.f, 0.f, 0.f, 0.f};

    const float* xp = X + (size_t)(mb + srow) * 1024 + sc4;
    // W frag base for this wave's 3 tiles; chunk index (nt*32+kc)*64+lane
    uint4 wr[2][6];
    #pragma unroll
    for (int jj = 0; jj < 3; jj++) {
        int nt = wave * 3 + jj;
        const uint4* wb = (const uint4*)(wpk + ((size_t)(nt * 32) * 64 + lane) * 8);
        wr[0][jj * 2]     = wb[0];          // kc=0 chunk: +64 lanes*16B per kc
        wr[0][jj * 2 + 1] = wb[64];         // kc=1
    }
    float4 xf = *(const float4*)xp;

    for (int it = 0; it < 16; it++) {
        const int cur = it & 1, nxt = cur ^ 1;
        // pack this chunk's X into LDS
        *(uint2*)&Xl[srow][sc4] = (uint2){ pack2_bf16(xf.x, xf.y), pack2_bf16(xf.z, xf.w) };
        __syncthreads();
        // prefetch next chunk (global; independent of LDS)
        if (it < 15) {
            xf = *(const float4*)(xp + (it + 1) * 64);
            #pragma unroll
            for (int jj = 0; jj < 3; jj++) {
                int nt = wave * 3 + jj;
                const uint4* wb = (const uint4*)(wpk + ((size_t)(nt * 32 + (it + 1) * 2) * 64 + lane) * 8);
                wr[nxt][jj * 2]     = wb[0];
                wr[nxt][jj * 2 + 1] = wb[64];
            }
        }
        bf16x8 a0 = *(const bf16x8*)&Xl[l15][grp * 8];
        bf16x8 a1 = *(const bf16x8*)&Xl[l15][32 + grp * 8];
        #pragma unroll
        for (int jj = 0; jj < 3; jj++) {
            U4B b0, b1; b0.u = wr[cur][jj * 2]; b1.u = wr[cur][jj * 2 + 1];
            acc[jj] = __builtin_amdgcn_mfma_f32_16x16x32_bf16(a0, b0.v, acc[jj], 0, 0, 0);
            acc[jj] = __builtin_amdgcn_mfma_f32_16x16x32_bf16(a1, b1.v, acc[jj], 0, 0, 0);
        }
        __syncthreads();
    }
    // epilogue (verified in R4): D row = grp*4+r, col = (wave*3+jj)*16+l15
    const int r0 = mb + grp * 4;
    const int bb = mb >> 11;
    const int t0 = (mb + grp * 4) & 2047;
    #pragma unroll
    for (int jj = 0; jj < 3; jj++) {
        int col = (wave * 3 + jj) * 16 + l15;
        if (col < 64) {
            for (int r = 0; r < 4; r++)
                qb[(size_t)(r0 + r) * 64 + col] = f32_to_bf16(acc[jj][r] * 0.03125f);
        } else if (col < 128) {
            for (int r = 0; r < 4; r++)
                kb[(size_t)(r0 + r) * 64 + (col - 64)] = f32_to_bf16(acc[jj][r]);
        } else {
            int c = col - 128;
            ushort4 vv;
            vv.x = f32_to_bf16(acc[jj][0]); vv.y = f32_to_bf16(acc[jj][1]);
            vv.z = f32_to_bf16(acc[jj][2]); vv.w = f32_to_bf16(acc[jj][3]);
            *(ushort4*)(vt + ((size_t)bb * 64 + c) * 2048 + t0) = vv;
        }
    }
}

// ---------------- Kernel 3: attention pass 1 --------------------------------
// 1-D grid 640, f-major decode: all heavy (8-tile) blocks of all batches
// dispatch first. Otherwise identical to the passing R4 kernel.
__global__ __launch_bounds__(256) void attn1_kernel(const unsigned short* __restrict__ qb,
        const unsigned short* __restrict__ kb, const unsigned short* __restrict__ vt,
        float* __restrict__ pm, float* __restrict__ pl, float* __restrict__ pacc) {
    __shared__ unsigned short Kl[2][64][72];   // [key][dim]
    __shared__ unsigned short Vl[2][64][72];   // [dim][key]
    const int tid = threadIdx.x;
    const int wave = tid >> 6, lane = tid & 63;
    const int grp = lane >> 4, l15 = lane & 15;
    const int b = blockIdx.x & 7;
    const int f = blockIdx.x >> 3;             // heavy-first (f=0 -> j=31,s=0)
    int s, j;
    if (f < 32)      { s = 0; j = 31 - f; }
    else if (f < 56) { s = 1; j = 31 - (f - 32); }
    else if (f < 72) { s = 2; j = 31 - (f - 56); }
    else             { s = 3; j = 31 - (f - 72); }
    const int qbase = j * 64 + wave * 16;
    const int ktend = min(8, j + 1 - 8 * s);

    const unsigned short* qp = qb + ((size_t)b * 2048 + qbase + l15) * 64 + grp * 8;
    bf16x8 bq0 = *(const bf16x8*)qp;
    bf16x8 bq1 = *(const bf16x8*)(qp + 32);

    float m_i = -1e30f, l_i = 0.f;
    f32x4 acc[4];
    for (int d = 0; d < 4; d++) acc[d] = (f32x4){0.f, 0.f, 0.f, 0.f};

    const unsigned short* kB = kb + ((size_t)b * 2048 + s * 512) * 64;
    const unsigned short* vB = vt + (size_t)b * 64 * 2048 + s * 512;
    const int r1 = tid >> 3, c1 = (tid & 7) * 8;
    const int r2 = (tid + 256) >> 3, c2 = c1;

    uint4 kr0, kr1, vr0, vr1;
    kr0 = *(const uint4*)(kB + (size_t)r1 * 64 + c1);
    kr1 = *(const uint4*)(kB + (size_t)r2 * 64 + c2);
    vr0 = *(const uint4*)(vB + (size_t)r1 * 2048 + c1);
    vr1 = *(const uint4*)(vB + (size_t)r2 * 2048 + c2);
    *(uint4*)&Kl[0][r1][c1] = kr0;  *(uint4*)&Kl[0][r2][c2] = kr1;
    *(uint4*)&Vl[0][r1][c1] = vr0;  *(uint4*)&Vl[0][r2][c2] = vr1;
    __syncthreads();

    for (int kt = 0; kt < ktend; kt++) {
        const int buf = kt & 1;
        const bool more = (kt + 1) < ktend;
        if (more) {
            const unsigned short* kN = kB + (size_t)(kt + 1) * 64 * 64;
            const unsigned short* vN = vB + (kt + 1) * 64;
            kr0 = *(const uint4*)(kN + (size_t)r1 * 64 + c1);
            kr1 = *(const uint4*)(kN + (size_t)r2 * 64 + c2);
            vr0 = *(const uint4*)(vN + (size_t)r1 * 2048 + c1);
            vr1 = *(const uint4*)(vN + (size_t)r2 * 2048 + c2);
        }
        const int keybase = s * 512 + kt * 64;
        f32x4 st[4];
        #pragma unroll
        for (int nt = 0; nt < 4; nt++) {
            bf16x8 a0 = *(const bf16x8*)&Kl[buf][nt * 16 + l15][grp * 8];
            bf16x8 a1 = *(const bf16x8*)&Kl[buf][nt * 16 + l15][32 + grp * 8];
            f32x4 t = (f32x4){0.f, 0.f, 0.f, 0.f};
            t = __builtin_amdgcn_mfma_f32_16x16x32_bf16(a0, bq0, t, 0, 0, 0);
            t = __builtin_amdgcn_mfma_f32_16x16x32_bf16(a1, bq1, t, 0, 0, 0);
            st[nt] = t;
        }
        if (keybase + 63 > qbase) {
            int q = qbase + l15;
            #pragma unroll
            for (int nt = 0; nt < 4; nt++)
                for (int r = 0; r < 4; r++)
                    if (keybase + nt * 16 + grp * 4 + r > q) st[nt][r] = -1e30f;
        }
        float tmax = -1e30f;
        #pragma unroll
        for (int nt = 0; nt < 4; nt++)
            for (int r = 0; r < 4; r++) tmax = fmaxf(tmax, st[nt][r]);
        tmax = fmaxf(tmax, __shfl_xor(tmax, 16, 64));
        tmax = fmaxf(tmax, __shfl_xor(tmax, 32, 64));
        float mnew = fmaxf(m_i, tmax);
        float alpha = __expf(m_i - mnew);
        m_i = mnew;
        float p[4][4]; float ts = 0.f;
        #pragma unroll
        for (int nt = 0; nt < 4; nt++)
            for (int r = 0; r < 4; r++) { p[nt][r] = __expf(st[nt][r] - mnew); ts += p[nt][r]; }
        ts += __shfl_xor(ts, 16, 64);
        ts += __shfl_xor(ts, 32, 64);
        l_i = l_i * alpha + ts;
        #pragma unroll
        for (int d = 0; d < 4; d++) acc[d] *= alpha;
        uint32_t t0a = pack2_bf16(p[0][0], p[0][1]), t0b = pack2_bf16(p[0][2], p[0][3]);
        uint32_t t1a = pack2_bf16(p[1][0], p[1][1]), t1b = pack2_bf16(p[1][2], p[1][3]);
        uint32_t t2a = pack2_bf16(p[2][0], p[2][1]), t2b = pack2_bf16(p[2][2], p[2][3]);
        uint32_t t3a = pack2_bf16(p[3][0], p[3][1]), t3b = pack2_bf16(p[3][2], p[3][3]);
        const int s0l = ((grp & 1) << 5) + l15, s1l = s0l + 16;
        const bool hi = (grp >= 2);
        U4B bw0, bw1;
        {
            uint32_t e0a = (uint32_t)__shfl((int)t0a, s0l, 64);
            uint32_t e0b = (uint32_t)__shfl((int)t0b, s0l, 64);
            uint32_t e0c = (uint32_t)__shfl((int)t0a, s1l, 64);
            uint32_t e0d = (uint32_t)__shfl((int)t0b, s1l, 64);
            uint32_t e1a = (uint32_t)__shfl((int)t1a, s0l, 64);
            uint32_t e1b = (uint32_t)__shfl((int)t1b, s0l, 64);
            uint32_t e1c = (uint32_t)__shfl((int)t1a, s1l, 64);
            uint32_t e1d = (uint32_t)__shfl((int)t1b, s1l, 64);
            bw0.u = (uint4){ hi ? e1a : e0a, hi ? e1b : e0b, hi ? e1c : e0c, hi ? e1d : e0d };
        }
        {
            uint32_t e0a = (uint32_t)__shfl((int)t2a, s0l, 64);
            uint32_t e0b = (uint32_t)__shfl((int)t2b, s0l, 64);
            uint32_t e0c = (uint32_t)__shfl((int)t2a, s1l, 64);
            uint32_t e0d = (uint32_t)__shfl((int)t2b, s1l, 64);
            uint32_t e1a = (uint32_t)__shfl((int)t3a, s0l, 64);
            uint32_t e1b = (uint32_t)__shfl((int)t3b, s0l, 64);
            uint32_t e1c = (uint32_t)__shfl((int)t3a, s1l, 64);
            uint32_t e1d = (uint32_t)__shfl((int)t3b, s1l, 64);
            bw1.u = (uint4){ hi ? e1a : e0a, hi ? e1b : e0b, hi ? e1c : e0c, hi ? e1d : e0d };
        }
        #pragma unroll
        for (int dt = 0; dt < 4; dt++) {
            bf16x8 av0 = *(const bf16x8*)&Vl[buf][dt * 16 + l15][grp * 8];
            bf16x8 av1 = *(const bf16x8*)&Vl[buf][dt * 16 + l15][32 + grp * 8];
            acc[dt] = __builtin_amdgcn_mfma_f32_16x16x32_bf16(av0, bw0.v, acc[dt], 0, 0, 0);
            acc[dt] = __builtin_amdgcn_mfma_f32_16x16x32_bf16(av1, bw1.v, acc[dt], 0, 0, 0);
        }
        if (more) {
            const int nb = buf ^ 1;
            *(uint4*)&Kl[nb][r1][c1] = kr0;  *(uint4*)&Kl[nb][r2][c2] = kr1;
            *(uint4*)&Vl[nb][r1][c1] = vr0;  *(uint4*)&Vl[nb][r2][c2] = vr1;
        }
        __syncthreads();
    }
    size_t rowq = (size_t)b * 2048 + qbase + l15;
    size_t p = rowq * 4 + s;
    if (grp == 0) { pm[p] = m_i; pl[p] = l_i; }
    #pragma unroll
    for (int dt = 0; dt < 4; dt++)
        *(f32x4*)&pacc[p * 64 + dt * 16 + grp * 4] = acc[dt];
}

// ---------------- Kernel 4: attention pass 2 (combine segments) ---------------
__global__ __launch_bounds__(256) void attn2_kernel(const float* __restrict__ pm,
        const float* __restrict__ pl, const float* __restrict__ pacc,
        float* __restrict__ out) {
    int idx = blockIdx.x * 256 + threadIdx.x;     // 16384*16
    int row = idx >> 4;
    int d0 = (idx & 15) * 4;
    int t = row & 2047;
    int ns = (t >> 9) + 1;
    float mv[4];
    float M = -1e30f;
    for (int s = 0; s < ns; s++) { mv[s] = pm[(size_t)row * 4 + s]; M = fmaxf(M, mv[s]); }
    float den = 0.f;
    f32x4 num = (f32x4){0.f, 0.f, 0.f, 0.f};
    for (int s = 0; s < ns; s++) {
        float w = __expf(mv[s] - M);
        den += w * pl[(size_t)row * 4 + s];
        f32x4 a = *(const f32x4*)&pacc[((size_t)row * 4 + s) * 64 + d0];
        num += w * a;
    }
    float inv = 1.f / den;
    *(f32x4*)&out[(size_t)row * 64 + d0] = num * inv;
}

extern "C" void kernel_launch(void* const* d_in, const int* in_sizes, int n_in,
                              void* d_out, int out_size, void* d_ws, size_t ws_size,
                              hipStream_t stream) {
    const float* X  = (const float*)d_in[0];
    const float* Wq = (const float*)d_in[1];
    const float* Wk = (const float*)d_in[2];
    const float* Wv = (const float*)d_in[3];
    float* out = (float*)d_out;

    unsigned short* qb  = (unsigned short*)d_ws;          // [16384][64] bf16 (q pre-scaled)
    unsigned short* kb  = qb + (size_t)M_ * 64;           // [16384][64]
    unsigned short* wpk = kb + (size_t)M_ * 64;           // [24576][8] frag-packed W
    unsigned short* vt  = wpk + (size_t)24576 * 8;        // [8][64][2048]
    float* pm   = (float*)(vt + (size_t)B_ * 64 * 2048);  // [16384][4]
    float* pl   = pm + (size_t)M_ * 4;                    // [16384][4]
    float* pacc = pl + (size_t)M_ * 4;                    // [16384][4][64]

    prepack_w<<<96, 256, 0, stream>>>(Wq, Wk, Wv, wpk);
    qkv_kernel<<<1024, 256, 0, stream>>>(X, wpk, qb, kb, vt);
    attn1_kernel<<<640, 256, 0, stream>>>(qb, kb, vt, pm, pl, pacc);
    attn2_kernel<<<1024, 256, 0, stream>>>(pm, pl, pacc, out);
}